// Round 4
// baseline (42.598 us; speedup 1.0000x reference)
//
#include <hip/hip_runtime.h>

typedef unsigned short u16;
typedef __attribute__((ext_vector_type(8))) short bf16x8;
typedef __attribute__((ext_vector_type(4))) float f32x4;

#define BATCH 16384
#define DIM   2048
#define NTASK 8
#define ODIM  128
#define KMASK 256   /* DIM / NTASK */
#define BM    64    /* rows per block */
#define CHUNK 16    /* rows per pipeline chunk */
#define NCH   4     /* BM / CHUNK */

__device__ __forceinline__ int task0_id(const float* __restrict__ t) {
    int t0 = 0;
#pragma unroll
    for (int j = 1; j < NTASK; ++j)
        if (t[j] > 0.5f) t0 = j;
    return t0;
}

// fp32 -> bf16 bits, round-nearest-even (inputs finite)
__device__ __forceinline__ unsigned f2bf_u(float f) {
    union { float f; unsigned u; } v; v.f = f;
    return (v.u + 0x7FFFu + ((v.u >> 16) & 1u)) >> 16;
}
__device__ __forceinline__ unsigned pack2(float a, float b) {
    return f2bf_u(a) | (f2bf_u(b) << 16);
}
__device__ __forceinline__ float dot4(float4 v) {
    return v.x * v.x + v.y * v.y + v.z * v.z + v.w * v.w;
}

// Single fused kernel: B-stationary (per-wave B slice in registers),
// A streamed through double-buffered LDS in 16-row chunks.
__global__ __launch_bounds__(512, 2)
void fused_kernel(const float* __restrict__ task,
                  const float* __restrict__ x,
                  const float* __restrict__ centers,
                  float* __restrict__ out) {
    __shared__ u16   As[2][CHUNK * KMASK];   // 2 x 8 KB, 16B-slot XOR swizzle
    __shared__ float x2s[2][CHUNK];          // -0.5 * masked row norms
    __shared__ float msks[BM][NTASK];        // per-row task mask

    const int tid  = threadIdx.x;
    const int w    = tid >> 6;     // wave 0..7, owns o in [w*16, w*16+16)
    const int lane = tid & 63;
    const int l15  = lane & 15;
    const int g    = lane >> 4;
    const int bm   = blockIdx.x * BM;
    const int t0   = task0_id(task);

    // per-row output masks for all 64 rows (one float per thread)
    msks[tid >> 3][tid & 7] = task[(size_t)(bm + (tid >> 3)) * NTASK + (tid & 7)];

    // ---- A loads: chunks 0,1 issued before the B section ----
    const int arow = tid >> 5;          // 0..15
    const int acol = (tid & 31) * 8;    // 8 floats per thread
    float4 a[NCH][2];
#pragma unroll
    for (int ch = 0; ch < 2; ++ch) {
        const float* xp =
            x + (size_t)(bm + ch * CHUNK + arow) * DIM + t0 * KMASK + acol;
        a[ch][0] = *reinterpret_cast<const float4*>(xp);
        a[ch][1] = *reinterpret_cast<const float4*>(xp + 4);
    }

    // ---- B: load fp32 slice once, convert to bf16 regs, fused w2 ----
    bf16x8 bv[4][8];                    // [c][ks] : 128 VGPR, lives whole kernel
    float  w2v[4] = {0.f, 0.f, 0.f, 0.f};
    {
        const float* cp =
            centers + (size_t)((w * 16 + l15) * 4) * DIM + t0 * KMASK + g * 8;
#pragma unroll
        for (int ks = 0; ks < 8; ++ks) {
#pragma unroll
            for (int c = 0; c < 4; ++c) {
                const float* p = cp + (size_t)c * DIM + ks * 32;
                float4 f0 = *reinterpret_cast<const float4*>(p);
                float4 f1 = *reinterpret_cast<const float4*>(p + 4);
                w2v[c] += dot4(f0) + dot4(f1);
                int4 q = make_int4((int)pack2(f0.x, f0.y), (int)pack2(f0.z, f0.w),
                                   (int)pack2(f1.x, f1.y), (int)pack2(f1.z, f1.w));
                bv[c][ks] = *reinterpret_cast<bf16x8*>(&q);
            }
        }
        // reduce over the 4 g-groups (lane bits 4,5); all lanes end with full sum
#pragma unroll
        for (int c = 0; c < 4; ++c) {
            w2v[c] += __shfl_xor(w2v[c], 16);
            w2v[c] += __shfl_xor(w2v[c], 32);
            w2v[c] *= -0.5f;
        }
    }

    // ---- A loads: chunks 2,3 (plenty of time before their converts) ----
#pragma unroll
    for (int ch = 2; ch < NCH; ++ch) {
        const float* xp =
            x + (size_t)(bm + ch * CHUNK + arow) * DIM + t0 * KMASK + acol;
        a[ch][0] = *reinterpret_cast<const float4*>(xp);
        a[ch][1] = *reinterpret_cast<const float4*>(xp + 4);
    }

    // ---- pipelined M-loop: one barrier per chunk, 2 LDS buffers ----
#pragma unroll
    for (int ch = 0; ch < NCH; ++ch) {
        // convert current chunk + fused x2 (fp32, pre-conversion values)
        float sq = dot4(a[ch][0]) + dot4(a[ch][1]);
        sq += __shfl_xor(sq, 1);
        sq += __shfl_xor(sq, 2);
        sq += __shfl_xor(sq, 4);
        sq += __shfl_xor(sq, 8);
        sq += __shfl_xor(sq, 16);
        if ((tid & 31) == 0) x2s[ch & 1][arow] = -0.5f * sq;
        {
            int4 q = make_int4(
                (int)pack2(a[ch][0].x, a[ch][0].y), (int)pack2(a[ch][0].z, a[ch][0].w),
                (int)pack2(a[ch][1].x, a[ch][1].y), (int)pack2(a[ch][1].z, a[ch][1].w));
            const int sw = (tid & 31) ^ (arow & 7);
            *reinterpret_cast<int4*>(&As[ch & 1][arow * KMASK + sw * 8]) = q;
        }
        __syncthreads();

        // MFMA: 8 ds_read_b128 + 32 MFMA per wave
        bf16x8 av[8];
#pragma unroll
        for (int ks = 0; ks < 8; ++ks) {
            const int sw2 = (ks * 4 + g) ^ (l15 & 7);
            av[ks] = *reinterpret_cast<const bf16x8*>(
                &As[ch & 1][l15 * KMASK + sw2 * 8]);
        }
        f32x4 acc[4];
#pragma unroll
        for (int c = 0; c < 4; ++c) acc[c] = (f32x4){0.f, 0.f, 0.f, 0.f};
#pragma unroll
        for (int ks = 0; ks < 8; ++ks)
#pragma unroll
            for (int c = 0; c < 4; ++c)
                acc[c] = __builtin_amdgcn_mfma_f32_16x16x32_bf16(
                    av[ks], bv[c][ks], acc[c], 0, 0, 0);

        // epilogue: fully in-lane (D: col=l15 -> o, row=g*4+r)
#pragma unroll
        for (int r = 0; r < 4; ++r) {
            const int row = g * 4 + r;
            const float xh = x2s[ch & 1][row];
            const float mk = msks[ch * CHUNK + row][w];
            const float e0 = __expf(acc[0][r] + xh + w2v[0]);
            const float e1 = __expf(acc[1][r] + xh + w2v[1]);
            const float e2 = __expf(acc[2][r] + xh + w2v[2]);
            const float e3 = __expf(acc[3][r] + xh + w2v[3]);
            const float S  = e0 + e1 + e2 + e3;
            const float Mx = fmaxf(fmaxf(e0, e1), fmaxf(e2, e3));
            const float P  = S / (S + 4.0f - 4.0f * Mx);
            out[(size_t)(bm + ch * CHUNK + row) * ODIM + w * 16 + l15] = P * mk;
        }
        // no trailing barrier needed: next chunk writes the other buffer, and
        // a wave 2 chunks ahead is fenced by the intervening barriers.
    }
}

extern "C" void kernel_launch(void* const* d_in, const int* in_sizes, int n_in,
                              void* d_out, int out_size, void* d_ws, size_t ws_size,
                              hipStream_t stream) {
    const float* task    = (const float*)d_in[0];   // [16384, 8]
    const float* x       = (const float*)d_in[1];   // [16384, 2048]
    const float* centers = (const float*)d_in[2];   // [128, 4, 2048]
    float* out = (float*)d_out;                     // [16384, 128]

    fused_kernel<<<dim3(BATCH / BM), dim3(512), 0, stream>>>(task, x, centers, out);
}

// Round 5
// 25.732 us; speedup vs baseline: 1.6554x; 1.6554x over previous
//
#include <hip/hip_runtime.h>

typedef unsigned short u16;
typedef __attribute__((ext_vector_type(8))) short bf16x8;
typedef __attribute__((ext_vector_type(4))) float f32x4;

#define BATCH 16384
#define DIM   2048
#define NTASK 8
#define ODIM  128
#define KMASK 256   /* DIM / NTASK */
#define OCN   512   /* ODIM * 4    */
#define BM    64    /* rows per main block */
#define NCH   4     /* 16-row chunks per block */

/* ws layout (bytes) */
#define OFF_B   (8u * 1024u * 1024u)            /* Abf: 16384*256 u16 = 8 MB   */
#define OFF_W2  (OFF_B + OCN * KMASK * 2u)      /* Bbf: 512*256 u16 = 256 KB   */
#define OFF_X2  (OFF_W2 + OCN * 4u)             /* w2c: 512 f32                */
#define OFF_MT  (OFF_X2 + BATCH * 4u)           /* x2w: 16384 f32              */

__device__ __forceinline__ int task0_id(const float* __restrict__ t) {
    int t0 = 0;
#pragma unroll
    for (int j = 1; j < NTASK; ++j)
        if (t[j] > 0.5f) t0 = j;
    return t0;
}

__device__ __forceinline__ u16 f2bf(float f) {
    union { float f; unsigned u; } v; v.f = f;
    return (u16)((v.u + 0x7FFFu + ((v.u >> 16) & 1u)) >> 16);
}
__device__ __forceinline__ float dot4(float4 v) {
    return v.x * v.x + v.y * v.y + v.z * v.z + v.w * v.w;
}

// One kernel, three block-roles:
//  [0,4096)    : x-slice -> bf16 Abf rows + x2w = -0.5*rownorm   (4 rows/blk)
//  [4096,4224) : centers slice -> c-major bf16 Bbf + w2c = -0.5*norm
//  [4224,4288) : task transpose -> mT[8][16384]
__global__ __launch_bounds__(256)
void prep_kernel(const float* __restrict__ task,
                 const float* __restrict__ x,
                 const float* __restrict__ centers,
                 u16* __restrict__ Abf, u16* __restrict__ Bbf,
                 float* __restrict__ w2c, float* __restrict__ x2w,
                 float* __restrict__ mT) {
    const int b    = blockIdx.x;
    const int tid  = threadIdx.x;
    const int lane = tid & 63;

    if (b < 4096) {
        const int t0  = task0_id(task);
        const int row = b * 4 + (tid >> 6);
        float4 v = *reinterpret_cast<const float4*>(
            x + (size_t)row * DIM + t0 * KMASK + lane * 4);
        float s = dot4(v);
#pragma unroll
        for (int off = 32; off; off >>= 1) s += __shfl_xor(s, off);
        if (lane == 0) x2w[row] = -0.5f * s;
        ushort4 bb;
        bb.x = f2bf(v.x); bb.y = f2bf(v.y); bb.z = f2bf(v.z); bb.w = f2bf(v.w);
        *reinterpret_cast<ushort4*>(Abf + (size_t)row * KMASK + lane * 4) = bb;
    } else if (b < 4224) {
        const int t0   = task0_id(task);
        const int oc   = (b - 4096) * 4 + (tid >> 6);
        const int rowp = (oc & 3) * ODIM + (oc >> 2);   // c*128 + o
        float4 v = *reinterpret_cast<const float4*>(
            centers + (size_t)oc * DIM + t0 * KMASK + lane * 4);
        float s = dot4(v);
#pragma unroll
        for (int off = 32; off; off >>= 1) s += __shfl_xor(s, off);
        if (lane == 0) w2c[rowp] = -0.5f * s;
        ushort4 bb;
        bb.x = f2bf(v.x); bb.y = f2bf(v.y); bb.z = f2bf(v.z); bb.w = f2bf(v.w);
        *reinterpret_cast<ushort4*>(Bbf + (size_t)rowp * KMASK + lane * 4) = bb;
    } else {
        const int row = (b - 4224) * 256 + tid;
        float4 m0 = *reinterpret_cast<const float4*>(task + (size_t)row * NTASK);
        float4 m1 = *reinterpret_cast<const float4*>(task + (size_t)row * NTASK + 4);
        mT[0 * BATCH + row] = m0.x; mT[1 * BATCH + row] = m0.y;
        mT[2 * BATCH + row] = m0.z; mT[3 * BATCH + row] = m0.w;
        mT[4 * BATCH + row] = m1.x; mT[5 * BATCH + row] = m1.y;
        mT[6 * BATCH + row] = m1.z; mT[7 * BATCH + row] = m1.w;
    }
}

// Pure-bf16 main: B-stationary in regs, A reg->LDS (XOR swizzle), 1 barrier.
__global__ __launch_bounds__(512, 2)
void gemm_kernel(const u16* __restrict__ Abf, const u16* __restrict__ Bbf,
                 const float* __restrict__ w2c, const float* __restrict__ x2w,
                 const float* __restrict__ mT, float* __restrict__ out) {
    __shared__ u16 As[NCH][16 * KMASK];   // 4 x 8 KB

    const int tid  = threadIdx.x;
    const int w    = tid >> 6;       // wave 0..7, o in [w*16, w*16+16)
    const int lane = tid & 63;
    const int l15  = lane & 15;
    const int g    = lane >> 4;
    const int bm   = blockIdx.x * BM;
    const int slot = lane & 31;
    const int row  = w * 2 + (lane >> 5);   // LDS row 0..15 this lane stages

    // ---- A stage loads first (deepest latency; 4 independent dwordx4) ----
    int4 areg[NCH];
#pragma unroll
    for (int ch = 0; ch < NCH; ++ch)
        areg[ch] = *reinterpret_cast<const int4*>(
            Abf + (size_t)(bm + ch * 16 + row) * KMASK + slot * 8);

    // ---- B stationary: 32 x bf16x8 = 128 VGPR, loaded once (L2) ----
    bf16x8 bv[4][8];
    {
        const u16* bp = Bbf + (size_t)(w * 16 + l15) * KMASK + g * 8;
#pragma unroll
        for (int c = 0; c < 4; ++c)
#pragma unroll
            for (int ks = 0; ks < 8; ++ks)
                bv[c][ks] = *reinterpret_cast<const bf16x8*>(
                    bp + (size_t)c * ODIM * KMASK + ks * 32);
    }
    float w2v[4];
#pragma unroll
    for (int c = 0; c < 4; ++c) w2v[c] = w2c[c * ODIM + w * 16 + l15];

    float4 x2v[NCH], mTv[NCH];
#pragma unroll
    for (int ch = 0; ch < NCH; ++ch) {
        x2v[ch] = *reinterpret_cast<const float4*>(x2w + bm + ch * 16 + g * 4);
        mTv[ch] = *reinterpret_cast<const float4*>(
            mT + (size_t)w * BATCH + bm + ch * 16 + g * 4);
    }

    // ---- LDS writes (swizzled) + the kernel's single barrier ----
#pragma unroll
    for (int ch = 0; ch < NCH; ++ch)
        *reinterpret_cast<int4*>(
            &As[ch][row * KMASK + (slot ^ (row & 7)) * 8]) = areg[ch];
    __syncthreads();

    // ---- 4 chunks: 8 ds_read_b128 + 32 MFMA + in-lane epilogue each ----
#pragma unroll
    for (int ch = 0; ch < NCH; ++ch) {
        bf16x8 av[8];
#pragma unroll
        for (int ks = 0; ks < 8; ++ks)
            av[ks] = *reinterpret_cast<const bf16x8*>(
                &As[ch][l15 * KMASK + ((ks * 4 + g) ^ (l15 & 7)) * 8]);

        f32x4 acc[4];
#pragma unroll
        for (int c = 0; c < 4; ++c) acc[c] = (f32x4){0.f, 0.f, 0.f, 0.f};
#pragma unroll
        for (int ks = 0; ks < 8; ++ks)
#pragma unroll
            for (int c = 0; c < 4; ++c)
                acc[c] = __builtin_amdgcn_mfma_f32_16x16x32_bf16(
                    av[ks], bv[c][ks], acc[c], 0, 0, 0);

        // D layout: col = l15 (o), row = g*4 + r
        const float* x2p = reinterpret_cast<const float*>(&x2v[ch]);
        const float* mkp = reinterpret_cast<const float*>(&mTv[ch]);
#pragma unroll
        for (int r = 0; r < 4; ++r) {
            const float xh = x2p[r];
            const float e0 = __expf(acc[0][r] + xh + w2v[0]);
            const float e1 = __expf(acc[1][r] + xh + w2v[1]);
            const float e2 = __expf(acc[2][r] + xh + w2v[2]);
            const float e3 = __expf(acc[3][r] + xh + w2v[3]);
            const float S  = e0 + e1 + e2 + e3;
            const float Mx = fmaxf(fmaxf(e0, e1), fmaxf(e2, e3));
            const float P  = S / (S + 4.0f - 4.0f * Mx);
            out[(size_t)(bm + ch * 16 + g * 4 + r) * ODIM + w * 16 + l15] =
                P * mkp[r];
        }
    }
}

extern "C" void kernel_launch(void* const* d_in, const int* in_sizes, int n_in,
                              void* d_out, int out_size, void* d_ws, size_t ws_size,
                              hipStream_t stream) {
    const float* task    = (const float*)d_in[0];   // [16384, 8]
    const float* x       = (const float*)d_in[1];   // [16384, 2048]
    const float* centers = (const float*)d_in[2];   // [128, 4, 2048]
    float* out = (float*)d_out;                     // [16384, 128]

    char* ws = (char*)d_ws;
    u16*   Abf = (u16*)ws;
    u16*   Bbf = (u16*)(ws + OFF_B);
    float* w2c = (float*)(ws + OFF_W2);
    float* x2w = (float*)(ws + OFF_X2);
    float* mT  = (float*)(ws + OFF_MT);

    prep_kernel<<<dim3(4288), dim3(256), 0, stream>>>(
        task, x, centers, Abf, Bbf, w2c, x2w, mT);
    gemm_kernel<<<dim3(BATCH / BM), dim3(512), 0, stream>>>(
        Abf, Bbf, w2c, x2w, mT, out);
}

// Round 6
// 24.741 us; speedup vs baseline: 1.7218x; 1.0401x over previous
//
#include <hip/hip_runtime.h>

typedef unsigned short u16;
typedef __attribute__((ext_vector_type(8))) short bf16x8;
typedef __attribute__((ext_vector_type(4))) float f32x4;

#define BATCH 16384
#define DIM   2048
#define NTASK 8
#define ODIM  128
#define KMASK 256   /* DIM / NTASK */
#define OCN   512   /* ODIM * 4    */
#define BM    64
#define NCH   4     /* 16-row chunks */

__device__ __forceinline__ int task0_id(const float* __restrict__ t) {
    int t0 = 0;
#pragma unroll
    for (int j = 1; j < NTASK; ++j)
        if (t[j] > 0.5f) t0 = j;
    return t0;
}

__device__ __forceinline__ unsigned f2bf_u(float f) {
    union { float f; unsigned u; } v; v.f = f;
    return (v.u + 0x7FFFu + ((v.u >> 16) & 1u)) >> 16;
}
__device__ __forceinline__ unsigned pack2(float a, float b) {
    return f2bf_u(a) | (f2bf_u(b) << 16);
}
__device__ __forceinline__ float dot4(float4 v) {
    return v.x * v.x + v.y * v.y + v.z * v.z + v.w * v.w;
}

// B-only prep: centers masked slice -> c-major bf16 Bbf[c*128+o][256],
// plus w2c[c*128+o] = -0.5 * ||w||^2. 128 blocks x 256 thr, one wave per oc.
__global__ __launch_bounds__(256)
void prep_kernel(const float* __restrict__ task,
                 const float* __restrict__ centers,
                 u16* __restrict__ Bbf, float* __restrict__ w2c) {
    const int oc   = blockIdx.x * 4 + (threadIdx.x >> 6);
    const int lane = threadIdx.x & 63;
    const int t0   = task0_id(task);
    const int rowp = (oc & 3) * ODIM + (oc >> 2);   // c*128 + o
    float4 v = *reinterpret_cast<const float4*>(
        centers + (size_t)oc * DIM + t0 * KMASK + lane * 4);
    float s = dot4(v);
#pragma unroll
    for (int off = 32; off; off >>= 1) s += __shfl_xor(s, off);
    if (lane == 0) w2c[rowp] = -0.5f * s;
    ushort4 bb;
    bb.x = (u16)f2bf_u(v.x); bb.y = (u16)f2bf_u(v.y);
    bb.z = (u16)f2bf_u(v.z); bb.w = (u16)f2bf_u(v.w);
    *reinterpret_cast<ushort4*>(Bbf + (size_t)rowp * KMASK + lane * 4) = bb;
}

// Main: inline A fp32->bf16 staging (one pass over x), B-stationary bf16 regs,
// one barrier, 4 x (8 ds_read_b128 + 32 MFMA + in-lane Gaussian epilogue).
__global__ __launch_bounds__(512, 2)
void gauss_kernel(const float* __restrict__ task,
                  const float* __restrict__ x,
                  const u16* __restrict__ Bbf,
                  const float* __restrict__ w2c,
                  float* __restrict__ out) {
    __shared__ u16   As[NCH][16 * KMASK];   // 32 KB, XOR-swizzled 16B slots
    __shared__ float x2s[BM];               // -0.5 * masked row norms
    __shared__ float msks[BM][NTASK];

    const int tid  = threadIdx.x;
    const int w    = tid >> 6;     // wave 0..7, o in [w*16, w*16+16)
    const int lane = tid & 63;
    const int l15  = lane & 15;
    const int g    = lane >> 4;
    const int bm   = blockIdx.x * BM;
    const int t0   = task0_id(task);

    // ---- A loads first: 8 independent float4 from HBM (deepest latency) ----
    const int srow = tid >> 3;          // 0..63
    const int scol = (tid & 7) * 32;    // 32 floats per thread
    const float* xp = x + (size_t)(bm + srow) * DIM + t0 * KMASK + scol;
    float4 xa[8];
#pragma unroll
    for (int i = 0; i < 8; ++i)
        xa[i] = *reinterpret_cast<const float4*>(xp + i * 4);

    // ---- B loads: 32 dwordx4 of bf16 from L2 (retire under A-pack) ----
    bf16x8 bv[4][8];
    {
        const u16* bp = Bbf + (size_t)(w * 16 + l15) * KMASK + g * 8;
#pragma unroll
        for (int c = 0; c < 4; ++c)
#pragma unroll
            for (int ks = 0; ks < 8; ++ks)
                bv[c][ks] = *reinterpret_cast<const bf16x8*>(
                    bp + (size_t)c * ODIM * KMASK + ks * 32);
    }
    float w2v[4];
#pragma unroll
    for (int c = 0; c < 4; ++c) w2v[c] = w2c[c * ODIM + w * 16 + l15];

    // masks: one float per thread covers all 64 rows x 8 tasks
    msks[srow][tid & 7] = task[(size_t)(bm + srow) * NTASK + (tid & 7)];

    // ---- pack A -> LDS (swizzled) + fused x2 ----
    float sq = 0.f;
#pragma unroll
    for (int i = 0; i < 8; ++i) sq += dot4(xa[i]);
    sq += __shfl_xor(sq, 1);
    sq += __shfl_xor(sq, 2);
    sq += __shfl_xor(sq, 4);
    if ((tid & 7) == 0) x2s[srow] = -0.5f * sq;

    const int ch_w = srow >> 4;
    const int rr   = srow & 15;
#pragma unroll
    for (int i = 0; i < 4; ++i) {
        int4 q = make_int4(
            (int)pack2(xa[2 * i].x, xa[2 * i].y),
            (int)pack2(xa[2 * i].z, xa[2 * i].w),
            (int)pack2(xa[2 * i + 1].x, xa[2 * i + 1].y),
            (int)pack2(xa[2 * i + 1].z, xa[2 * i + 1].w));
        const int slot = (tid & 7) * 4 + i;
        const int sw   = slot ^ (rr & 7);
        *reinterpret_cast<int4*>(&As[ch_w][rr * KMASK + sw * 8]) = q;
    }
    __syncthreads();

    // ---- 4 chunks: ds_read + MFMA + epilogue ----
#pragma unroll
    for (int ch = 0; ch < NCH; ++ch) {
        bf16x8 av[8];
#pragma unroll
        for (int ks = 0; ks < 8; ++ks)
            av[ks] = *reinterpret_cast<const bf16x8*>(
                &As[ch][l15 * KMASK + ((ks * 4 + g) ^ (l15 & 7)) * 8]);

        f32x4 acc[4];
#pragma unroll
        for (int c = 0; c < 4; ++c) acc[c] = (f32x4){0.f, 0.f, 0.f, 0.f};
#pragma unroll
        for (int ks = 0; ks < 8; ++ks)
#pragma unroll
            for (int c = 0; c < 4; ++c)
                acc[c] = __builtin_amdgcn_mfma_f32_16x16x32_bf16(
                    av[ks], bv[c][ks], acc[c], 0, 0, 0);

        // D layout: col = l15 (o), row = g*4 + r
#pragma unroll
        for (int r = 0; r < 4; ++r) {
            const int row = ch * 16 + g * 4 + r;
            const float xh = x2s[row];
            const float mk = msks[row][w];
            const float e0 = __expf(acc[0][r] + xh + w2v[0]);
            const float e1 = __expf(acc[1][r] + xh + w2v[1]);
            const float e2 = __expf(acc[2][r] + xh + w2v[2]);
            const float e3 = __expf(acc[3][r] + xh + w2v[3]);
            const float S  = e0 + e1 + e2 + e3;
            const float Mx = fmaxf(fmaxf(e0, e1), fmaxf(e2, e3));
            const float P  = S / (S + 4.0f - 4.0f * Mx);
            out[(size_t)(bm + row) * ODIM + w * 16 + l15] = P * mk;
        }
    }
}

extern "C" void kernel_launch(void* const* d_in, const int* in_sizes, int n_in,
                              void* d_out, int out_size, void* d_ws, size_t ws_size,
                              hipStream_t stream) {
    const float* task    = (const float*)d_in[0];   // [16384, 8]
    const float* x       = (const float*)d_in[1];   // [16384, 2048]
    const float* centers = (const float*)d_in[2];   // [128, 4, 2048]
    float* out = (float*)d_out;                     // [16384, 128]

    u16*   Bbf = (u16*)d_ws;                                   // 256 KB
    float* w2c = (float*)((char*)d_ws + OCN * KMASK * 2u);     // 2 KB

    prep_kernel<<<dim3(OCN / 4), dim3(256), 0, stream>>>(task, centers, Bbf, w2c);
    gauss_kernel<<<dim3(BATCH / BM), dim3(512), 0, stream>>>(
        task, x, Bbf, w2c, out);
}